// Round 6
// baseline (290.425 us; speedup 1.0000x reference)
//
#include <hip/hip_runtime.h>
#include <hip/hip_bf16.h>

typedef __bf16          bf16x8_t __attribute__((ext_vector_type(8)));
typedef float           f32x4_t  __attribute__((ext_vector_type(4)));
typedef unsigned short  u16x4_t  __attribute__((ext_vector_type(4)));

#define DIN      256
#define CONDN    128
#define BM       64
#define NTHREADS 1024   // 16 waves; block shape forces 4 waves/SIMD -> 128-reg unified cap
#define NWAVE    16

// d_ws bf16 layout (element offsets): W^T, i.e. [N][K] row-major, K contiguous
#define OFF_WS1 0        // [512][128]
#define OFF_WS2 65536    // [512][512]
#define OFF_WS3 327680   // [128][512]
#define OFF_WT1 393216   // [512][128]
#define OFF_WT2 458752   // [512][512]
#define OFF_WT3 720896   // [128][512]
#define W_TOTAL 786432

__global__ void prep_w(const float* __restrict__ Ws1, const float* __restrict__ Ws2,
                       const float* __restrict__ Ws3, const float* __restrict__ Wt1,
                       const float* __restrict__ Wt2, const float* __restrict__ Wt3,
                       __hip_bfloat16* __restrict__ wt) {
  int idx = blockIdx.x * blockDim.x + threadIdx.x;
  if (idx >= W_TOTAL) return;
  const float* W; int K, N, off;
  if (idx < OFF_WS2)      { W = Ws1; K = 128; N = 512; off = idx - OFF_WS1; }
  else if (idx < OFF_WS3) { W = Ws2; K = 512; N = 512; off = idx - OFF_WS2; }
  else if (idx < OFF_WT1) { W = Ws3; K = 512; N = 128; off = idx - OFF_WS3; }
  else if (idx < OFF_WT2) { W = Wt1; K = 128; N = 512; off = idx - OFF_WT1; }
  else if (idx < OFF_WT3) { W = Wt2; K = 512; N = 512; off = idx - OFF_WT2; }
  else                    { W = Wt3; K = 512; N = 128; off = idx - OFF_WT3; }
  int n = off / K;
  int k = off - n * K;
  wt[idx] = __float2bfloat16(W[k * N + n]);   // transpose: WT[n][k] = W[k][n]
}

// Swizzled LDS element offset within a row: 8-elem (16 B) granules, g ^= (row&7).
#define SWZ(row, col) (((((col) >> 3) ^ ((row) & 7)) << 3) + ((col) & 7))

// out[rows m*16+..][n-slice] += A[..][0:KTOT] * W^T[n-slice][0:KTOT]
// A in swizzled LDS (row stride lda); B rows (stride LDB, K contiguous) direct
// from global (L2-resident), depth-2 static prefetch ring (fully unrolled).
template<int KTOT, int LDB, int MTT, int NT>
__device__ __forceinline__ void mm_tile(const __hip_bfloat16* __restrict__ As, const int lda,
                                        const __hip_bfloat16* __restrict__ Bsrc,
                                        const int l15, const int l4, f32x4_t acc[MTT][NT]) {
  const int xr = l15 & 7;
  const __hip_bfloat16* bp = Bsrc + (size_t)l15 * LDB + l4 * 8;
  constexpr int NS = KTOT / 32;
  constexpr int DEPTH = (NS < 2) ? NS : 2;
  bf16x8_t ring[DEPTH][NT];
  bf16x8_t a[MTT];
  #pragma unroll
  for (int p = 0; p < DEPTH; ++p) {
    #pragma unroll
    for (int n = 0; n < NT; ++n)
      ring[p][n] = *reinterpret_cast<const bf16x8_t*>(bp + (size_t)n * 16 * LDB + p * 32);
  }
  #pragma unroll
  for (int s = 0; s < NS; ++s) {
    #pragma unroll
    for (int m = 0; m < MTT; ++m)
      a[m] = *reinterpret_cast<const bf16x8_t*>(
          &As[(m * 16 + l15) * lda + (((s * 4 + l4) ^ xr) << 3)]);
    #pragma unroll
    for (int m = 0; m < MTT; ++m) {
      #pragma unroll
      for (int n = 0; n < NT; ++n)
        acc[m][n] = __builtin_amdgcn_mfma_f32_16x16x32_bf16(a[m], ring[s % DEPTH][n], acc[m][n], 0, 0, 0);
    }
    if (s + DEPTH < NS) {
      #pragma unroll
      for (int n = 0; n < NT; ++n)
        ring[s % DEPTH][n] = *reinterpret_cast<const bf16x8_t*>(bp + (size_t)n * 16 * LDB + (s + DEPTH) * 32);
    }
  }
}

template<int MTT, int NT, int LD>
__device__ __forceinline__ void relu_store(f32x4_t acc[MTT][NT], const float* __restrict__ bias,
                                           const int n0, const int l15, const int l4,
                                           __hip_bfloat16* __restrict__ H) {
  #pragma unroll
  for (int n = 0; n < NT; ++n) {
    const int col = n0 + n * 16 + l15;
    const float bv = bias[col];
    #pragma unroll
    for (int m = 0; m < MTT; ++m) {
      #pragma unroll
      for (int r = 0; r < 4; ++r) {
        const int row = m * 16 + l4 * 4 + r;
        float v = fmaxf(acc[m][n][r] + bv, 0.0f);
        H[row * LD + SWZ(row, col)] = __float2bfloat16(v);
      }
    }
  }
}

#define ZERO_ACC(acc, MTT, NT) do {                       \
    _Pragma("unroll") for (int m_ = 0; m_ < MTT; ++m_)    \
    _Pragma("unroll") for (int n_ = 0; n_ < NT; ++n_)     \
      acc[m_][n_] = (f32x4_t){0.f, 0.f, 0.f, 0.f};        \
  } while (0)

__global__ __launch_bounds__(NTHREADS, 1)
void realnvp_fused(const float* __restrict__ x, const __hip_bfloat16* __restrict__ wt,
                   const float* __restrict__ bs1, const float* __restrict__ bs2,
                   const float* __restrict__ bs3, const float* __restrict__ bt1,
                   const float* __restrict__ bt2, const float* __restrict__ bt3,
                   float* __restrict__ y, float* __restrict__ ld) {
  __shared__ __hip_bfloat16 sA[BM * CONDN];   // 16 KB, swizzled
  __shared__ __hip_bfloat16 sH[BM * 512];     // 64 KB, swizzled, reused 4x
  // total 80 KB
  float* sLd = reinterpret_cast<float*>(sA);  // [8][BM] overlay; sA dead after t-L1

  const int tid  = threadIdx.x;
  const int lane = tid & 63;
  const int wid  = tid >> 6;        // 0..15
  const int l15  = lane & 15;
  const int l4   = lane >> 4;
  const int row0 = blockIdx.x * BM;
  const int n0   = wid * 32;        // layer 1/2 column slice (NT=2)
  const int wA   = wid & 7;
  const int n3   = wA * 16;         // layer 3 column slice
  const int rb   = (wid >> 3) * 32; // layer 3 row half (MT=2 over 32 rows)

  // ---- stage cond tile (fp32 -> bf16 swizzled LDS) and copy cond to y (exact fp32) ----
  #pragma unroll
  for (int i = 0; i < 2; ++i) {
    int f = tid + i * NTHREADS;              // 2048 float4 chunks: 64 rows x 32
    int r = f >> 5;
    int c = (f & 31) << 2;
    const float4 v = *reinterpret_cast<const float4*>(&x[(size_t)(row0 + r) * DIN + c]);
    *reinterpret_cast<float4*>(&y[(size_t)(row0 + r) * DIN + c]) = v;
    union { u16x4_t u; __hip_bfloat16 b[4]; } p;
    p.b[0] = __float2bfloat16(v.x); p.b[1] = __float2bfloat16(v.y);
    p.b[2] = __float2bfloat16(v.z); p.b[3] = __float2bfloat16(v.w);
    *reinterpret_cast<u16x4_t*>(&sA[r * CONDN + SWZ(r, c)]) = p.u;
  }
  __syncthreads();   // B1: sA ready

  f32x4_t acc[4][2];
  f32x4_t sfrag[2], tfrag[2];

  // ===================== MLP s =====================
  ZERO_ACC(acc, 4, 2);
  mm_tile<128, 128, 4, 2>(sA, CONDN, wt + OFF_WS1 + (size_t)n0 * 128, l15, l4, acc);
  relu_store<4, 2, 512>(acc, bs1, n0, l15, l4, sH);
  __syncthreads();   // B2: sH = h1s
  ZERO_ACC(acc, 4, 2);
  mm_tile<512, 512, 4, 2>(sH, 512, wt + OFF_WS2 + (size_t)n0 * 512, l15, l4, acc);
  __syncthreads();   // B3: all h1s reads done
  relu_store<4, 2, 512>(acc, bs2, n0, l15, l4, sH);
  __syncthreads();   // B4: sH = h2s
  {
    // layer 3 s: wave = (row half rb) x (col slice n3), full K=512, result in regs
    f32x4_t a3[2][1];
    ZERO_ACC(a3, 2, 1);
    mm_tile<512, 512, 2, 1>(sH + rb * 512, 512, wt + OFF_WS3 + (size_t)n3 * 512, l15, l4, a3);
    sfrag[0] = a3[0][0]; sfrag[1] = a3[1][0];
  }
  __syncthreads();   // B5: all h2s reads done

  // ===================== MLP t =====================
  ZERO_ACC(acc, 4, 2);
  mm_tile<128, 128, 4, 2>(sA, CONDN, wt + OFF_WT1 + (size_t)n0 * 128, l15, l4, acc);
  relu_store<4, 2, 512>(acc, bt1, n0, l15, l4, sH);
  __syncthreads();   // B6: sH = h1t; sA dead from here (sLd overlay safe)
  ZERO_ACC(acc, 4, 2);
  mm_tile<512, 512, 4, 2>(sH, 512, wt + OFF_WT2 + (size_t)n0 * 512, l15, l4, acc);
  __syncthreads();   // B7: all h1t reads done
  relu_store<4, 2, 512>(acc, bt2, n0, l15, l4, sH);
  __syncthreads();   // B8: sH = h2t
  {
    f32x4_t a3[2][1];
    ZERO_ACC(a3, 2, 1);
    mm_tile<512, 512, 2, 1>(sH + rb * 512, 512, wt + OFF_WT3 + (size_t)n3 * 512, l15, l4, a3);
    tfrag[0] = a3[0][0]; tfrag[1] = a3[1][0];
  }

  // ===================== epilogue (all 16 waves; wave owns rows rb..rb+31 x cols n3..n3+15) ====
  const float bsv = bs3[n3 + l15];
  const float btv = bt3[n3 + l15];
  #pragma unroll
  for (int m = 0; m < 2; ++m) {
    #pragma unroll
    for (int r = 0; r < 4; ++r) {
      const int rl   = rb + m * 16 + l4 * 4 + r;
      const int grow = row0 + rl;
      const int col  = n3 + l15;
      float s = tanhf(sfrag[m][r] + bsv);
      float t = tfrag[m][r] + btv;
      float xv = x[(size_t)grow * DIN + CONDN + col];
      y[(size_t)grow * DIN + CONDN + col] = xv * expf(s) + t;
      float ss = s;
      ss += __shfl_xor(ss, 1);
      ss += __shfl_xor(ss, 2);
      ss += __shfl_xor(ss, 4);
      ss += __shfl_xor(ss, 8);
      if (l15 == 0) sLd[wA * BM + rl] = ss;   // 8 col-partials per row
    }
  }
  __syncthreads();   // B9: partials ready
  if (tid < BM) {
    float v = 0.f;
    #pragma unroll
    for (int w = 0; w < 8; ++w) v += sLd[w * BM + tid];
    ld[row0 + tid] = v;
  }
}

extern "C" void kernel_launch(void* const* d_in, const int* in_sizes, int n_in,
                              void* d_out, int out_size, void* d_ws, size_t ws_size,
                              hipStream_t stream) {
  const float* x   = (const float*)d_in[0];
  const float* Ws1 = (const float*)d_in[1];
  const float* bs1 = (const float*)d_in[2];
  const float* Ws2 = (const float*)d_in[3];
  const float* bs2 = (const float*)d_in[4];
  const float* Ws3 = (const float*)d_in[5];
  const float* bs3 = (const float*)d_in[6];
  const float* Wt1 = (const float*)d_in[7];
  const float* bt1 = (const float*)d_in[8];
  const float* Wt2 = (const float*)d_in[9];
  const float* bt2 = (const float*)d_in[10];
  const float* Wt3 = (const float*)d_in[11];
  const float* bt3 = (const float*)d_in[12];

  const int Btot = in_sizes[0] / DIN;          // 65536
  float* y  = (float*)d_out;
  float* ld = (float*)d_out + (size_t)Btot * DIN;
  __hip_bfloat16* wt = (__hip_bfloat16*)d_ws;  // 1.5 MB needed

  prep_w<<<(W_TOTAL + 255) / 256, 256, 0, stream>>>(Ws1, Ws2, Ws3, Wt1, Wt2, Wt3, wt);
  realnvp_fused<<<Btot / BM, NTHREADS, 0, stream>>>(x, wt, bs1, bs2, bs3,
                                                    bt1, bt2, bt3, y, ld);
}

// Round 7
// 244.274 us; speedup vs baseline: 1.1889x; 1.1889x over previous
//
#include <hip/hip_runtime.h>
#include <hip/hip_bf16.h>

typedef __bf16          bf16x8_t __attribute__((ext_vector_type(8)));
typedef float           f32x4_t  __attribute__((ext_vector_type(4)));
typedef unsigned short  u16x4_t  __attribute__((ext_vector_type(4)));

#define DIN      256
#define CONDN    128
#define BM       64
#define NTHREADS 512
#define NWAVE    8
#define BUFE     16384   // elems per sW staging buffer (32 KB)

// d_ws bf16 layout (element offsets). Each layer is stored CHUNK-LINEAR:
// per 32-k tile: chunk c = o*N + n (o = k-octet 0..3, n = col), 8 elems/chunk.
// So DMA staging reads are contiguous and LDS layout == global layout.
#define OFF_WS1 0        // K=128, N=512
#define OFF_WS2 65536    // K=512, N=512
#define OFF_WS3 327680   // K=512, N=128
#define OFF_WT1 393216
#define OFF_WT2 458752
#define OFF_WT3 720896
#define W_TOTAL 786432

__global__ void prep_w(const float* __restrict__ Ws1, const float* __restrict__ Ws2,
                       const float* __restrict__ Ws3, const float* __restrict__ Wt1,
                       const float* __restrict__ Wt2, const float* __restrict__ Wt3,
                       __hip_bfloat16* __restrict__ wt) {
  int idx = blockIdx.x * blockDim.x + threadIdx.x;
  if (idx >= W_TOTAL) return;
  const float* W; int lgN, off;
  if (idx < OFF_WS2)      { W = Ws1; lgN = 9; off = OFF_WS1; }
  else if (idx < OFF_WS3) { W = Ws2; lgN = 9; off = OFF_WS2; }
  else if (idx < OFF_WT1) { W = Ws3; lgN = 7; off = OFF_WS3; }
  else if (idx < OFF_WT2) { W = Wt1; lgN = 9; off = OFF_WT1; }
  else if (idx < OFF_WT3) { W = Wt2; lgN = 9; off = OFF_WT2; }
  else                    { W = Wt3; lgN = 7; off = OFF_WT3; }
  const int e    = idx - off;
  const int lgT  = lgN + 5;                 // tile = N*32 elems
  const int tile = e >> lgT;
  const int rem  = e & ((1 << lgT) - 1);
  const int c    = rem >> 3;                // chunk
  const int j    = rem & 7;
  const int o    = c >> lgN;                // k-octet in tile
  const int n    = c & ((1 << lgN) - 1);    // col
  const int k    = tile * 32 + o * 8 + j;
  wt[idx] = __float2bfloat16(W[(k << lgN) + n]);
}

// Swizzled LDS element offset within a row: 8-elem (16 B) granules, g ^= (row&7).
#define SWZ(row, col) (((((col) >> 3) ^ ((row) & 7)) << 3) + ((col) & 7))

// Stage one chunk-linear weight tile (NTILE cols x 32 k = NTILE*64 bytes) into
// LDS via async DMA. Wave-uniform LDS dst; per-lane contiguous 16B global src.
template<int NTILE>
__device__ __forceinline__ void stage_w(__hip_bfloat16* __restrict__ dstbuf,
                                        const __hip_bfloat16* __restrict__ src0,
                                        const int wid, const int lane) {
  constexpr int ROUNDS = (NTILE * 4) / 512;   // chunks / (8 waves * 64 lanes)
  #pragma unroll
  for (int r = 0; r < ROUNDS; ++r) {
    const int cbase = (r * 8 + wid) * 64;                    // wave-uniform
    const __hip_bfloat16* src = src0 + (size_t)(cbase + lane) * 8;
    __hip_bfloat16* dst = dstbuf + (size_t)cbase * 8;        // + lane*16B by HW
    __builtin_amdgcn_global_load_lds(
        (const __attribute__((address_space(1))) void*)src,
        (__attribute__((address_space(3))) void*)dst, 16, 0, 0);
  }
}

// One layer slice: acc += A[0:64][0:NS*32] * W^T. A from swizzled LDS
// (a-frags prefetched 1 step ahead); W streamed tile-by-tile through sW
// double-buffer via global_load_lds (issued before compute, drained at the
// per-step barrier -> DMA overlaps MFMA). next_stage stages the NEXT
// segment's tile 0 on the last step, keeping the tile stream seamless.
template<int NS, int NTILE, int MTT, int NT, class NextFn>
__device__ __forceinline__ void gemm_layer(
    const __hip_bfloat16* __restrict__ As, const int lda,
    const __hip_bfloat16* __restrict__ wseg, __hip_bfloat16* __restrict__ sW,
    unsigned& tc, const int wid, const int lane, const int l15, const int l4,
    const int n0, f32x4_t acc[MTT][NT], NextFn next_stage)
{
  const int xr = l15 & 7;
  bf16x8_t a[MTT], an[MTT], b[NT];
  #pragma unroll
  for (int m = 0; m < MTT; ++m)
    a[m] = *reinterpret_cast<const bf16x8_t*>(&As[(m * 16 + l15) * lda + ((l4 ^ xr) << 3)]);
  #pragma unroll 1
  for (int s = 0; s < NS; ++s) {
    __hip_bfloat16* nbuf = sW + ((tc + 1) & 1) * BUFE;
    if (s + 1 < NS) stage_w<NTILE>(nbuf, wseg + (size_t)(s + 1) * (NTILE * 32), wid, lane);
    else            next_stage(nbuf);
    const __hip_bfloat16* cbuf = sW + (tc & 1) * BUFE;
    #pragma unroll
    for (int n = 0; n < NT; ++n)
      b[n] = *reinterpret_cast<const bf16x8_t*>(&cbuf[(size_t)(l4 * NTILE + n0 + n * 16 + l15) * 8]);
    if (s + 1 < NS) {
      #pragma unroll
      for (int m = 0; m < MTT; ++m)
        an[m] = *reinterpret_cast<const bf16x8_t*>(
            &As[(m * 16 + l15) * lda + ((((s + 1) * 4 + l4) ^ xr) << 3)]);
    }
    #pragma unroll
    for (int m = 0; m < MTT; ++m) {
      #pragma unroll
      for (int n = 0; n < NT; ++n)
        acc[m][n] = __builtin_amdgcn_mfma_f32_16x16x32_bf16(a[m], b[n], acc[m][n], 0, 0, 0);
    }
    if (s + 1 < NS) {
      #pragma unroll
      for (int m = 0; m < MTT; ++m) a[m] = an[m];
    }
    ++tc;
    __syncthreads();   // drains DMA (tile tc+1 ready) + joins waves
  }
}

template<int MTT, int NT, int LD>
__device__ __forceinline__ void relu_store(f32x4_t acc[MTT][NT], const float* __restrict__ bias,
                                           const int n0, const int l15, const int l4,
                                           __hip_bfloat16* __restrict__ H) {
  #pragma unroll
  for (int n = 0; n < NT; ++n) {
    const int col = n0 + n * 16 + l15;
    const float bv = bias[col];
    #pragma unroll
    for (int m = 0; m < MTT; ++m) {
      #pragma unroll
      for (int r = 0; r < 4; ++r) {
        const int row = m * 16 + l4 * 4 + r;
        float v = fmaxf(acc[m][n][r] + bv, 0.0f);
        H[row * LD + SWZ(row, col)] = __float2bfloat16(v);
      }
    }
  }
}

#define ZERO_ACC(acc, MTT, NT) do {                       \
    _Pragma("unroll") for (int m_ = 0; m_ < MTT; ++m_)    \
    _Pragma("unroll") for (int n_ = 0; n_ < NT; ++n_)     \
      acc[m_][n_] = (f32x4_t){0.f, 0.f, 0.f, 0.f};        \
  } while (0)

__global__ __launch_bounds__(NTHREADS, 1)
void realnvp_fused(const float* __restrict__ x, const __hip_bfloat16* __restrict__ wt,
                   const float* __restrict__ bs1, const float* __restrict__ bs2,
                   const float* __restrict__ bs3, const float* __restrict__ bt1,
                   const float* __restrict__ bt2, const float* __restrict__ bt3,
                   float* __restrict__ y, float* __restrict__ ld) {
  __shared__ __hip_bfloat16 sA[BM * CONDN];   // 16 KB, swizzled
  __shared__ __hip_bfloat16 sH[BM * 512];     // 64 KB, swizzled, reused 4x
  __shared__ __hip_bfloat16 sW[2 * BUFE];     // 64 KB, weight-tile double buffer
  float* sLd = reinterpret_cast<float*>(sA);  // overlay; sA dead after t-L1

  const int tid  = threadIdx.x;
  const int lane = tid & 63;
  const int wid  = tid >> 6;
  const int l15  = lane & 15;
  const int l4   = lane >> 4;
  const int row0 = blockIdx.x * BM;
  const int n064 = wid * 64;   // layer 1/2 column slice (NT=4)
  const int n3   = wid * 16;   // layer 3 column slice (NT=1)

  // prologue: kick off DMA of s-L1 tile 0 while we stage cond
  stage_w<512>(sW, wt + OFF_WS1, wid, lane);

  // stage cond tile (fp32 -> bf16 swizzled LDS) and copy cond to y (exact fp32)
  #pragma unroll
  for (int i = 0; i < 4; ++i) {
    int f = tid + i * NTHREADS;              // 2048 float4 chunks: 64 rows x 32
    int r = f >> 5;
    int c = (f & 31) << 2;
    const float4 v = *reinterpret_cast<const float4*>(&x[(size_t)(row0 + r) * DIN + c]);
    *reinterpret_cast<float4*>(&y[(size_t)(row0 + r) * DIN + c]) = v;
    union { u16x4_t u; __hip_bfloat16 b[4]; } p;
    p.b[0] = __float2bfloat16(v.x); p.b[1] = __float2bfloat16(v.y);
    p.b[2] = __float2bfloat16(v.z); p.b[3] = __float2bfloat16(v.w);
    *reinterpret_cast<u16x4_t*>(&sA[r * CONDN + SWZ(r, c)]) = p.u;
  }
  __syncthreads();   // B1: sA + W tile 0 ready

  unsigned tc = 0;
  f32x4_t acc[4][4];
  f32x4_t sfrag[4], tfrag[4];

  // ===================== MLP s =====================
  ZERO_ACC(acc, 4, 4);
  gemm_layer<4, 512, 4, 4>(sA, CONDN, wt + OFF_WS1, sW, tc, wid, lane, l15, l4, n064, acc,
      [&](__hip_bfloat16* nbuf) { stage_w<512>(nbuf, wt + OFF_WS2, wid, lane); });
  relu_store<4, 4, 512>(acc, bs1, n064, l15, l4, sH);
  __syncthreads();   // sH = h1s

  ZERO_ACC(acc, 4, 4);
  gemm_layer<16, 512, 4, 4>(sH, 512, wt + OFF_WS2, sW, tc, wid, lane, l15, l4, n064, acc,
      [&](__hip_bfloat16* nbuf) { stage_w<128>(nbuf, wt + OFF_WS3, wid, lane); });
  relu_store<4, 4, 512>(acc, bs2, n064, l15, l4, sH);
  __syncthreads();   // sH = h2s

  {
    f32x4_t a3[4][1];
    ZERO_ACC(a3, 4, 1);
    gemm_layer<16, 128, 4, 1>(sH, 512, wt + OFF_WS3, sW, tc, wid, lane, l15, l4, n3, a3,
        [&](__hip_bfloat16* nbuf) { stage_w<512>(nbuf, wt + OFF_WT1, wid, lane); });
    #pragma unroll
    for (int m = 0; m < 4; ++m) sfrag[m] = a3[m][0];
  }
  // trailing barrier inside gemm_layer: all h2s reads complete

  // ===================== MLP t =====================
  ZERO_ACC(acc, 4, 4);
  gemm_layer<4, 512, 4, 4>(sA, CONDN, wt + OFF_WT1, sW, tc, wid, lane, l15, l4, n064, acc,
      [&](__hip_bfloat16* nbuf) { stage_w<512>(nbuf, wt + OFF_WT2, wid, lane); });
  relu_store<4, 4, 512>(acc, bt1, n064, l15, l4, sH);
  __syncthreads();   // sH = h1t; sA dead from here (sLd overlay safe)

  ZERO_ACC(acc, 4, 4);
  gemm_layer<16, 512, 4, 4>(sH, 512, wt + OFF_WT2, sW, tc, wid, lane, l15, l4, n064, acc,
      [&](__hip_bfloat16* nbuf) { stage_w<128>(nbuf, wt + OFF_WT3, wid, lane); });
  relu_store<4, 4, 512>(acc, bt2, n064, l15, l4, sH);
  __syncthreads();   // sH = h2t

  {
    f32x4_t a3[4][1];
    ZERO_ACC(a3, 4, 1);
    gemm_layer<16, 128, 4, 1>(sH, 512, wt + OFF_WT3, sW, tc, wid, lane, l15, l4, n3, a3,
        [&](__hip_bfloat16*) {});
    #pragma unroll
    for (int m = 0; m < 4; ++m) tfrag[m] = a3[m][0];
  }

  // ===================== epilogue =====================
  const float bsv = bs3[n3 + l15];
  const float btv = bt3[n3 + l15];
  #pragma unroll
  for (int m = 0; m < 4; ++m) {
    #pragma unroll
    for (int r = 0; r < 4; ++r) {
      const int rl   = m * 16 + l4 * 4 + r;
      const int grow = row0 + rl;
      const int col  = n3 + l15;
      float s = tanhf(sfrag[m][r] + bsv);
      float t = tfrag[m][r] + btv;
      float xv = x[(size_t)grow * DIN + CONDN + col];
      y[(size_t)grow * DIN + CONDN + col] = xv * expf(s) + t;
      float ss = s;
      ss += __shfl_xor(ss, 1);
      ss += __shfl_xor(ss, 2);
      ss += __shfl_xor(ss, 4);
      ss += __shfl_xor(ss, 8);
      if (l15 == 0) sLd[wid * BM + rl] = ss;
    }
  }
  __syncthreads();
  if (tid < BM) {
    float v = 0.f;
    #pragma unroll
    for (int w = 0; w < NWAVE; ++w) v += sLd[w * BM + tid];
    ld[row0 + tid] = v;
  }
}

extern "C" void kernel_launch(void* const* d_in, const int* in_sizes, int n_in,
                              void* d_out, int out_size, void* d_ws, size_t ws_size,
                              hipStream_t stream) {
  const float* x   = (const float*)d_in[0];
  const float* Ws1 = (const float*)d_in[1];
  const float* bs1 = (const float*)d_in[2];
  const float* Ws2 = (const float*)d_in[3];
  const float* bs2 = (const float*)d_in[4];
  const float* Ws3 = (const float*)d_in[5];
  const float* bs3 = (const float*)d_in[6];
  const float* Wt1 = (const float*)d_in[7];
  const float* bt1 = (const float*)d_in[8];
  const float* Wt2 = (const float*)d_in[9];
  const float* bt2 = (const float*)d_in[10];
  const float* Wt3 = (const float*)d_in[11];
  const float* bt3 = (const float*)d_in[12];

  const int Btot = in_sizes[0] / DIN;          // 65536
  float* y  = (float*)d_out;
  float* ld = (float*)d_out + (size_t)Btot * DIN;
  __hip_bfloat16* wt = (__hip_bfloat16*)d_ws;  // 1.5 MB needed

  prep_w<<<(W_TOTAL + 255) / 256, 256, 0, stream>>>(Ws1, Ws2, Ws3, Wt1, Wt2, Wt3, wt);
  realnvp_fused<<<Btot / BM, NTHREADS, 0, stream>>>(x, wt, bs1, bs2, bs3,
                                                    bt1, bt2, bt3, y, ld);
}